// Round 7
// baseline (229.459 us; speedup 1.0000x reference)
//
#include <hip/hip_runtime.h>
#include <stdint.h>

#define B_ 4
#define S_ 2048
#define E_ 1024
#define D_ 1024   // attention dim

typedef short  bf16x8 __attribute__((ext_vector_type(8)));
typedef float  f32x4  __attribute__((ext_vector_type(4)));

// fp32 -> bf16 round-to-nearest-even
static __device__ __forceinline__ unsigned short f2bf(float f) {
    unsigned int u = __float_as_uint(f);
    u += 0x7fffu + ((u >> 16) & 1u);
    return (unsigned short)(u >> 16);
}

// async global->LDS, 16B per lane. LDS dest = wave-uniform base + lane*16.
static __device__ __forceinline__ void async16(const unsigned short* g, unsigned short* l) {
    auto gp = (const __attribute__((address_space(1))) void*)(uintptr_t)g;
    auto lp = (__attribute__((address_space(3))) void*)(uintptr_t)l;
    __builtin_amdgcn_global_load_lds(gp, lp, 16, 0, 0);
}

// ---------------------------------------------------------------------------
// LDS sub-tile unit (BK=64): row = 128 B = 8 chunks of 16 B. XOR swizzle:
// global chunk q of row r -> LDS chunk q^(r&7). One async16 covers 8 rows:
// lane l -> row +(l>>3), global chunk (l&7)^(l>>3). Reader k-half s reads
// chunk (s*4+quad)^(r&7). Conflict-free (SQ_LDS_BANK_CONFLICT=0, measured).
//
// R7: R6 proved counted-vmcnt on a 2-phase/depth-1 structure is null (matches
// the regime gate: T4 needs phase-split + depth>=2). proj rebuilt as the
// faithful T3+T4 schedule: BM=256 BN=128 BK=64, 8 waves (2Mx4N), TRIPLE
// buffer (144 KB LDS), DEPTH-2 prefetch: iter kt stages tile kt+2 (6 loads/
// thread split 3+3 across 2 phases), iter-end s_waitcnt vmcnt(6) -> only
// guarantees tile kt+1 landed, NEVER drains in steady state. Per K-tile:
// 2 phases x {stage 3 || ds_read 12/8 b128 || s_barrier || lgkmcnt(0)+
// sched_barrier || setprio(1) 16 MFMA setprio(0) || s_barrier}. Grid 768 =
// 3 EXACT rounds of 256 CUs (R5's partial-round tail fixed); XCD-bijective
// decode: each XCD owns 4 consecutive my panels (2 MB A in L2) x all ny.
// Hazards: stage buf (kt+2)%3 disjoint from compute buf kt%3 and in-flight
// (kt+1)%3; WAR on (kt-1)%3 safe behind iter-(kt-1) trailing barrier;
// RAW: every wave passes vmcnt(6) before the iter-end barrier, so all
// waves' tile-(kt+1) strips are in LDS when any wave reads them.
// exp/pv/convert: reverted to R4 forms (R6 counted variant was null).
// ---------------------------------------------------------------------------

// Kernel 0: fp32 -> bf16 convert (x -> xb, [Wk;Wq;Wv] -> Wb). Grid-stride.
__global__ __launch_bounds__(256)
void convert_kernel(const float* __restrict__ x,  const float* __restrict__ Wk,
                    const float* __restrict__ Wq, const float* __restrict__ Wv,
                    unsigned short* __restrict__ xb, unsigned short* __restrict__ Wb)
{
    const long long total  = (long long)B_ * S_ * E_ + 3LL * D_ * E_;  // 11534336
    const long long stride = (long long)gridDim.x * 256 * 4;
    for (long long idx = ((long long)blockIdx.x * 256 + threadIdx.x) * 4;
         idx < total; idx += stride) {
        const float* src; unsigned short* dst; long long off;
        if (idx < (long long)B_ * S_ * E_) {
            src = x; dst = xb; off = idx;
        } else {
            long long w = idx - (long long)B_ * S_ * E_;
            const int sel = (int)(w >> 20);          // 2^20 elems per W
            off = w & 1048575LL;
            src = (sel == 0) ? Wk : (sel == 1) ? Wq : Wv;
            dst = Wb + ((long long)sel << 20);
        }
        const float4 f = *(const float4*)(src + off);
        ushort4 u = { f2bf(f.x), f2bf(f.y), f2bf(f.z), f2bf(f.w) };
        *(ushort4*)(dst + off) = u;
    }
}

// ---------------------------------------------------------------------------
// Kernel 1: projections — 256x128 tile, depth-2 counted-vmcnt triple-buffer
// (see header). C[m,n] = sum_e xb[m,e]*Wb[n,e]; ny<8 -> K, <16 -> Q (x1/32),
// else V (transposed store). Dynamic LDS 147456 B. Grid 768, 512 threads.
// ---------------------------------------------------------------------------
__global__ __launch_bounds__(512, 2)
void proj_kernel(const unsigned short* __restrict__ xb,
                 const unsigned short* __restrict__ Wb,
                 unsigned short* __restrict__ Qb,
                 unsigned short* __restrict__ Kb,
                 unsigned short* __restrict__ Vt)
{
    extern __shared__ __align__(16) unsigned short lds[];
    // A: [3][16384] elems at 0 (32KB/buf); B: [3][8192] elems at 49152 (16KB/buf)

    const int bid = blockIdx.x;
    const int xcd = bid & 7, ii = bid >> 3;        // 768 = 8 XCDs x 96
    const int my = xcd * 4 + ii / 24;              // 0..31 (bijective)
    const int ny = ii % 24;                        // 0..23
    const int m0 = my * 256;
    const int wsel = ny >> 3;                      // 0=K 1=Q 2=V
    const int nloc = (ny & 7) * 128;

    const int t = threadIdx.x;
    const int lane = t & 63, wave = t >> 6;        // 8 waves
    const int l15 = lane & 15, quad = lane >> 4;
    const int wm2 = wave & 1, wn4 = wave >> 1;     // 2M x 4N
    const int lr = lane >> 3;
    const int lc = ((lane & 7) ^ lr) * 8;
    const int l7 = l15 & 7;

    const unsigned short* gA = xb + (size_t)(m0 + lr) * E_ + lc;
    const unsigned short* gB = Wb + (size_t)(ny * 128 + lr) * E_ + lc;
    const int uA = wave * 4;   // this wave's 4 A-units (unit = 8 rows x 64 k)
    const int uB = wave * 2;   // this wave's 2 B-units

    f32x4 acc[8][2];
    #pragma unroll
    for (int i = 0; i < 8; i++)
        #pragma unroll
        for (int j = 0; j < 2; j++) acc[i][j] = {0.f, 0.f, 0.f, 0.f};

    // prologue: tile 0 -> buf 0, tile 1 -> buf 1 (12 loads/thread)
    #pragma unroll
    for (int j = 0; j < 4; j++) async16(gA + (size_t)((uA + j) * 8) * E_, lds + (uA + j) * 512);
    #pragma unroll
    for (int j = 0; j < 2; j++) async16(gB + (size_t)((uB + j) * 8) * E_, lds + 49152 + (uB + j) * 512);
    #pragma unroll
    for (int j = 0; j < 4; j++) async16(gA + (size_t)((uA + j) * 8) * E_ + 64, lds + 16384 + (uA + j) * 512);
    #pragma unroll
    for (int j = 0; j < 2; j++) async16(gB + (size_t)((uB + j) * 8) * E_ + 64, lds + 49152 + 8192 + (uB + j) * 512);
    asm volatile("s_waitcnt vmcnt(6)" ::: "memory");   // tile 0 landed; tile 1 in flight
    __builtin_amdgcn_s_barrier();

    int cbuf = 0;
    for (int kt = 0; kt < 16; kt++) {
        const unsigned short* Ac = lds + cbuf * 16384;
        const unsigned short* Bc = lds + 49152 + cbuf * 8192;
        const int sbuf = (cbuf >= 1) ? (cbuf - 1) : 2;       // (kt+2)%3
        unsigned short* An = lds + sbuf * 16384;
        unsigned short* Bn = lds + 49152 + sbuf * 8192;
        const int k0n = (kt + 2) * 64;
        const bool st = (kt < 14);

        // ---------- phase 0: stage 3 | read A-frags 0..3 + B-frags | 16 MFMA
        if (st) {
            async16(gA + (size_t)((uA + 0) * 8) * E_ + k0n, An + (uA + 0) * 512);
            async16(gA + (size_t)((uA + 1) * 8) * E_ + k0n, An + (uA + 1) * 512);
            async16(gA + (size_t)((uA + 2) * 8) * E_ + k0n, An + (uA + 2) * 512);
        }
        bf16x8 af[4][2], bfv[2][2];
        #pragma unroll
        for (int s = 0; s < 2; s++) {
            const int cs = ((s * 4 + quad) ^ l7) * 8;
            #pragma unroll
            for (int mf = 0; mf < 4; mf++)
                af[mf][s] = *(const bf16x8*)&Ac[(wm2 * 128 + mf * 16 + l15) * 64 + cs];
            #pragma unroll
            for (int nf = 0; nf < 2; nf++)
                bfv[nf][s] = *(const bf16x8*)&Bc[(wn4 * 32 + nf * 16 + l15) * 64 + cs];
        }
        __builtin_amdgcn_s_barrier();
        asm volatile("s_waitcnt lgkmcnt(0)" ::: "memory");
        __builtin_amdgcn_sched_barrier(0);
        __builtin_amdgcn_s_setprio(1);
        #pragma unroll
        for (int s = 0; s < 2; s++)
            #pragma unroll
            for (int mf = 0; mf < 4; mf++)
                #pragma unroll
                for (int nf = 0; nf < 2; nf++)
                    acc[mf][nf] = __builtin_amdgcn_mfma_f32_16x16x32_bf16(
                        af[mf][s], bfv[nf][s], acc[mf][nf], 0, 0, 0);
        __builtin_amdgcn_s_setprio(0);
        __builtin_amdgcn_s_barrier();

        // ---------- phase 1: stage 3 | read A-frags 4..7 | 16 MFMA
        if (st) {
            async16(gA + (size_t)((uA + 3) * 8) * E_ + k0n, An + (uA + 3) * 512);
            async16(gB + (size_t)((uB + 0) * 8) * E_ + k0n, Bn + (uB + 0) * 512);
            async16(gB + (size_t)((uB + 1) * 8) * E_ + k0n, Bn + (uB + 1) * 512);
        }
        bf16x8 ag[4][2];
        #pragma unroll
        for (int s = 0; s < 2; s++) {
            const int cs = ((s * 4 + quad) ^ l7) * 8;
            #pragma unroll
            for (int mf = 0; mf < 4; mf++)
                ag[mf][s] = *(const bf16x8*)&Ac[(wm2 * 128 + (4 + mf) * 16 + l15) * 64 + cs];
        }
        __builtin_amdgcn_s_barrier();
        asm volatile("s_waitcnt lgkmcnt(0)" ::: "memory");
        __builtin_amdgcn_sched_barrier(0);
        __builtin_amdgcn_s_setprio(1);
        #pragma unroll
        for (int s = 0; s < 2; s++)
            #pragma unroll
            for (int mf = 0; mf < 4; mf++)
                #pragma unroll
                for (int nf = 0; nf < 2; nf++)
                    acc[4 + mf][nf] = __builtin_amdgcn_mfma_f32_16x16x32_bf16(
                        ag[mf][s], bfv[nf][s], acc[4 + mf][nf], 0, 0, 0);
        __builtin_amdgcn_s_setprio(0);

        // ---------- iter end: counted wait (tile kt+1 landed), barrier
        if (st) asm volatile("s_waitcnt vmcnt(6)" ::: "memory");
        else    asm volatile("s_waitcnt vmcnt(0)" ::: "memory");
        __builtin_amdgcn_s_barrier();
        cbuf = (cbuf >= 2) ? 0 : cbuf + 1;
    }

    // epilogue: wave owns rows m0+wm2*128+[0,128), cols nloc+wn4*32+[0,32)
    if (wsel == 0) {
        #pragma unroll
        for (int mf = 0; mf < 8; mf++)
            #pragma unroll
            for (int nf = 0; nf < 2; nf++) {
                const int gn = nloc + wn4 * 32 + nf * 16 + l15;
                #pragma unroll
                for (int r = 0; r < 4; r++) {
                    const int gm = m0 + wm2 * 128 + mf * 16 + quad * 4 + r;
                    Kb[(size_t)gm * D_ + gn] = f2bf(acc[mf][nf][r]);
                }
            }
    } else if (wsel == 1) {
        #pragma unroll
        for (int mf = 0; mf < 8; mf++)
            #pragma unroll
            for (int nf = 0; nf < 2; nf++) {
                const int gn = nloc + wn4 * 32 + nf * 16 + l15;
                #pragma unroll
                for (int r = 0; r < 4; r++) {
                    const int gm = m0 + wm2 * 128 + mf * 16 + quad * 4 + r;
                    Qb[(size_t)gm * D_ + gn] = f2bf(acc[mf][nf][r] * 0.03125f);
                }
            }
    } else {
        #pragma unroll
        for (int mf = 0; mf < 8; mf++)
            #pragma unroll
            for (int nf = 0; nf < 2; nf++) {
                const int s0 = m0 + wm2 * 128 + mf * 16 + quad * 4;
                const int b  = s0 >> 11, sl = s0 & (S_ - 1);
                const int gn = nloc + wn4 * 32 + nf * 16 + l15;
                ushort4 u = { f2bf(acc[mf][nf][0]), f2bf(acc[mf][nf][1]),
                              f2bf(acc[mf][nf][2]), f2bf(acc[mf][nf][3]) };
                *(ushort4*)&Vt[((size_t)(b << 10) + gn) * S_ + sl] = u;
            }
    }
}

// ---------------------------------------------------------------------------
// Kernel 2: E = exp(Qs K^T), causal, bf16 -> P. 128x128 tile, BK=64,
// single-buffered 32 KB LDS. COMPACT grid (136 tri-tiles, B), heavy-first.
// Scores bounded (|s| ~< 2). rowpart[b][nt*2+wn][row].  (R4 form)
// ---------------------------------------------------------------------------
__global__ __launch_bounds__(256, 4)
void expscores_kernel(const unsigned short* __restrict__ Qb,
                      const unsigned short* __restrict__ Kb,
                      unsigned short* __restrict__ P,
                      float* __restrict__ rowpart)
{
    int rem = blockIdx.x;
    int mt = 15, cnt = 16;
    while (rem >= cnt) { rem -= cnt; mt--; cnt--; }
    const int nt = rem;
    const int b  = blockIdx.y;

    __shared__ __align__(16) unsigned short As[128 * 64];
    __shared__ __align__(16) unsigned short Bs[128 * 64];

    const int t = threadIdx.x;
    const int m0 = mt * 128, n0 = nt * 128;

    const int lane = t & 63, wave = t >> 6;
    const int l15 = lane & 15, quad = lane >> 4;
    const int wm = wave & 1, wn = wave >> 1;
    const int sr = lane >> 3;
    const int sq = ((lane & 7) ^ sr) * 8;
    const int l7 = l15 & 7;

    const unsigned short* gA = Qb + (size_t)b * S_ * D_ + (size_t)(m0 + wave * 32 + sr) * D_ + sq;
    const unsigned short* gB = Kb + (size_t)b * S_ * D_ + (size_t)(n0 + wave * 32 + sr) * D_ + sq;
    unsigned short* lA = &As[wave * 2048];
    unsigned short* lB = &Bs[wave * 2048];

    f32x4 acc[4][4];
    #pragma unroll
    for (int i = 0; i < 4; i++)
        #pragma unroll
        for (int j = 0; j < 4; j++) acc[i][j] = {0.f, 0.f, 0.f, 0.f};

    for (int kt = 0; kt < 16; kt++) {
        const int k0 = kt * 64;
        __syncthreads();
        #pragma unroll
        for (int i = 0; i < 4; i++) {
            async16(gA + k0 + i * 8 * D_, lA + i * 512);
            async16(gB + k0 + i * 8 * D_, lB + i * 512);
        }
        __syncthreads();

        #pragma unroll
        for (int s = 0; s < 2; s++) {
            const int cs = ((s * 4 + quad) ^ l7) * 8;
            bf16x8 af[4], bfr[4];
            #pragma unroll
            for (int i = 0; i < 4; i++)
                af[i] = *(const bf16x8*)&As[(wm * 64 + i * 16 + l15) * 64 + cs];
            #pragma unroll
            for (int j = 0; j < 4; j++)
                bfr[j] = *(const bf16x8*)&Bs[(wn * 64 + j * 16 + l15) * 64 + cs];
            #pragma unroll
            for (int i = 0; i < 4; i++)
                #pragma unroll
                for (int j = 0; j < 4; j++)
                    acc[i][j] = __builtin_amdgcn_mfma_f32_16x16x32_bf16(af[i], bfr[j], acc[i][j], 0, 0, 0);
        }
    }

    unsigned short* Pb = P + (size_t)b * S_ * S_;
    #pragma unroll
    for (int i = 0; i < 4; i++)
        #pragma unroll
        for (int j = 0; j < 4; j++) {
            const int gn = n0 + wn * 64 + j * 16 + l15;
            #pragma unroll
            for (int r = 0; r < 4; r++) {
                const int gm = m0 + wm * 64 + i * 16 + quad * 4 + r;
                const float e = (gn <= gm) ? __expf(acc[i][j][r]) : 0.f;
                acc[i][j][r] = e;
                Pb[(size_t)gm * S_ + gn] = f2bf(e);
            }
        }

    float* rp = rowpart + ((size_t)b * 32 + nt * 2 + wn) * S_;
    #pragma unroll
    for (int i = 0; i < 4; i++) {
        float rsub[4];
        #pragma unroll
        for (int r = 0; r < 4; r++) {
            float s = acc[i][0][r] + acc[i][1][r] + acc[i][2][r] + acc[i][3][r];
            #pragma unroll
            for (int off = 8; off; off >>= 1) s += __shfl_xor(s, off);
            rsub[r] = s;
        }
        if (l15 == 0) {
            #pragma unroll
            for (int r = 0; r < 4; r++)
                rp[m0 + wm * 64 + i * 16 + quad * 4 + r] = rsub[r];
        }
    }
}

// ---------------------------------------------------------------------------
// Kernel 3: out = (E @ V) / rowsum. 128x128 tile, BK=64, DOUBLE-BUFFERED
// (LDS 64 KB, 2 blocks/CU). Grid (8 nt FAST, 16 y, B); mt = (b&2)?y:15-y so
// co-resident pairs have complementary iteration counts -> uniform 36
// iters/CU. rowsum gather hoisted before the K-loop.  (R4 form)
// ---------------------------------------------------------------------------
__global__ __launch_bounds__(256, 2)
void pv_kernel(const unsigned short* __restrict__ P,
               const unsigned short* __restrict__ Vt,
               const float* __restrict__ rowpart,
               float* __restrict__ out)
{
    const int nt = blockIdx.x;
    const int yy = blockIdx.y;
    const int b  = blockIdx.z;
    const int mt = (b & 2) ? yy : (15 - yy);  // complementary pairing across b

    __shared__ __align__(16) unsigned short As[2 * 128 * 64];
    __shared__ __align__(16) unsigned short Bs[2 * 128 * 64];

    const int t = threadIdx.x;
    const int m0 = mt * 128, n0 = nt * 128;
    const int niter = 2 * mt + 2;             // kend = m0+128, BK=64

    const int lane = t & 63, wave = t >> 6;
    const int l15 = lane & 15, quad = lane >> 4;
    const int wm = wave & 1, wn = wave >> 1;
    const int sr = lane >> 3;
    const int sq = ((lane & 7) ^ sr) * 8;
    const int l7 = l15 & 7;

    const unsigned short* gA = P  + (size_t)b * S_ * S_ + (size_t)(m0 + wave * 32 + sr) * S_ + sq;
    const unsigned short* gB = Vt + (size_t)b * D_ * S_ + (size_t)(n0 + wave * 32 + sr) * S_ + sq;
    unsigned short* lA = &As[wave * 2048];
    unsigned short* lB = &Bs[wave * 2048];

    // 1/rowsum gather issued before the K-loop (hides under prologue staging)
    const float* rp = rowpart + (size_t)b * 32 * S_ + (m0 + wm * 64 + lane);
    float rsum = 0.f;
    for (int k = 0; k < niter; k++) rsum += rp[(size_t)k * S_];
    const float invr = 1.0f / rsum;

    f32x4 acc[4][4];
    #pragma unroll
    for (int i = 0; i < 4; i++)
        #pragma unroll
        for (int j = 0; j < 4; j++) acc[i][j] = {0.f, 0.f, 0.f, 0.f};

    // prologue: stage k=0 into buffer 0
    #pragma unroll
    for (int i = 0; i < 4; i++) {
        async16(gA + i * 8 * S_, lA + i * 512);
        async16(gB + i * 8 * S_, lB + i * 512);
    }

    int buf = 0;
    for (int kt = 0; kt < niter; kt++) {
        __syncthreads();
        if (kt + 1 < niter) {
            const int k0 = (kt + 1) * 64;
            const int nb = (buf ^ 1) * 8192;
            #pragma unroll
            for (int i = 0; i < 4; i++) {
                async16(gA + k0 + i * 8 * S_, lA + nb + i * 512);
                async16(gB + k0 + i * 8 * S_, lB + nb + i * 512);
            }
        }
        const unsigned short* Ac = As + buf * 8192;
        const unsigned short* Bc = Bs + buf * 8192;
        #pragma unroll
        for (int s = 0; s < 2; s++) {
            const int cs = ((s * 4 + quad) ^ l7) * 8;
            bf16x8 af[4], bfr[4];
            #pragma unroll
            for (int i = 0; i < 4; i++)
                af[i] = *(const bf16x8*)&Ac[(wm * 64 + i * 16 + l15) * 64 + cs];
            #pragma unroll
            for (int j = 0; j < 4; j++)
                bfr[j] = *(const bf16x8*)&Bc[(wn * 64 + j * 16 + l15) * 64 + cs];
            #pragma unroll
            for (int i = 0; i < 4; i++)
                #pragma unroll
                for (int j = 0; j < 4; j++)
                    acc[i][j] = __builtin_amdgcn_mfma_f32_16x16x32_bf16(af[i], bfr[j], acc[i][j], 0, 0, 0);
        }
        buf ^= 1;
    }

    #pragma unroll
    for (int i = 0; i < 4; i++) {
        #pragma unroll
        for (int r = 0; r < 4; r++) {
            const float vr = __shfl(invr, i * 16 + quad * 4 + r);
            const int gm = m0 + wm * 64 + i * 16 + quad * 4 + r;
            #pragma unroll
            for (int j = 0; j < 4; j++) {
                const int gn = n0 + wn * 64 + j * 16 + l15;
                out[((size_t)b * S_ + gm) * D_ + gn] = rintf(acc[i][j][r] * vr * 1e4f) * 1e-4f;
            }
        }
    }
}

// ---------------------------------------------------------------------------
// Workspace (~85 MB):
//   [0,     16.7M)  Qb bf16 [4][2048][1024]
//   [16.7M, 33.5M)  Kb bf16
//   [33.5M, 50.3M)  Vt bf16 [4][1024][2048]
//   [50.3M, 83.9M)  P  bf16 [4][2048][2048]
//       xb (16.7M) + Wb (6.3M) overlay the start of P's region (dead before
//       expscores writes P).
//   [83.9M, +1M)    rowpart fp32 [4][32][2048]
// ---------------------------------------------------------------------------
extern "C" void kernel_launch(void* const* d_in, const int* in_sizes, int n_in,
                              void* d_out, int out_size, void* d_ws, size_t ws_size,
                              hipStream_t stream)
{
    (void)in_sizes; (void)n_in; (void)out_size; (void)ws_size;
    const float* x  = (const float*)d_in[0];
    const float* Wk = (const float*)d_in[1];
    const float* Wq = (const float*)d_in[2];
    const float* Wv = (const float*)d_in[3];
    float* out = (float*)d_out;

    char* ws = (char*)d_ws;
    unsigned short* Qb = (unsigned short*)ws;
    unsigned short* Kb = Qb + (size_t)B_ * S_ * D_;
    unsigned short* Vt = Kb + (size_t)B_ * S_ * D_;
    unsigned short* P  = Vt + (size_t)B_ * D_ * S_;
    unsigned short* xb = P;                                  // overlay (dead early)
    unsigned short* Wb = xb + (size_t)B_ * S_ * E_;
    float* rowpart = (float*)(P + (size_t)B_ * S_ * S_);

    convert_kernel  <<<2048, 256, 0, stream>>>(x, Wk, Wq, Wv, xb, Wb);
    proj_kernel     <<<dim3(768, 1, 1), 512, 147456, stream>>>(xb, Wb, Qb, Kb, Vt);
    expscores_kernel<<<dim3(136, B_, 1), 256, 0, stream>>>(Qb, Kb, P, rowpart);
    pv_kernel       <<<dim3(8, 16, B_),  256, 0, stream>>>(P, Vt, rowpart, out);
}